// Round 7
// baseline (7588.841 us; speedup 1.0000x reference)
//
#include <hip/hip_runtime.h>

#define T_STEPS 2048
#define NBATCH  1024

typedef _Float16 f16x8 __attribute__((ext_vector_type(8)));
typedef float    f32x4 __attribute__((ext_vector_type(4)));

__device__ __forceinline__ float sigm(float v) {
    float e = exp2f(-1.442695040888963f * v);
    return __builtin_amdgcn_rcpf(1.0f + e);
}
__device__ __forceinline__ float tanh_fast(float v) {
    float e = exp2f(2.885390081777927f * v);
    return fmaf(-2.0f, __builtin_amdgcn_rcpf(1.0f + e), 1.0f);
}

// load 8 consecutive fp32 -> 8 fp16 (RNE) fragment
__device__ __forceinline__ f16x8 loadrow8(const float* p) {
    float4 lo = *reinterpret_cast<const float4*>(p);
    float4 hi = *reinterpret_cast<const float4*>(p + 4);
    f16x8 r;
    r[0] = (_Float16)lo.x; r[1] = (_Float16)lo.y;
    r[2] = (_Float16)lo.z; r[3] = (_Float16)lo.w;
    r[4] = (_Float16)hi.x; r[5] = (_Float16)hi.y;
    r[6] = (_Float16)hi.z; r[7] = (_Float16)hi.w;
    return r;
}

// One block = one wave = 16 batch columns for all T steps.
// Same MFMA layout as R6 (verified: lane l, tile m holds i,f,g,o of unit
// 8*(l>>4)+m for batch l&15; per-tile h results ARE the lane's next B-frag
// elements -> zero cross-lane in the recurrence).
// NEW: weight A-fragments live in LDS (pre-swizzled fp16, 40 KB), re-read
// every step via ds_read_b128 -- compiler-proof residency, no remat/spill.
__global__ __launch_bounds__(64, 1)
void lstm3_mfma_kernel(const float* __restrict__ x,
                       const float* __restrict__ Wih0, const float* __restrict__ Whh0,
                       const float* __restrict__ bih0, const float* __restrict__ bhh0,
                       const float* __restrict__ Wih1, const float* __restrict__ Whh1,
                       const float* __restrict__ bih1, const float* __restrict__ bhh1,
                       const float* __restrict__ Wih2, const float* __restrict__ Whh2,
                       const float* __restrict__ bih2, const float* __restrict__ bhh2,
                       const float* __restrict__ Wfc,  const float* __restrict__ bfc,
                       float* __restrict__ out)
{
    const int l  = threadIdx.x;       // 0..63
    const int g  = l >> 4;            // lane group (k-chunk / C row-group)
    const int b  = l & 15;            // batch column within tile
    const int qa = l & 3;             // gate index for A-row loads
    const int gp = (l & 15) >> 2;     // unit group for A-row loads
    const int b0 = blockIdx.x * 16;   // batch-tile base

    // ---- LDS: 5 matrices x 8 tiles x 64 lanes x 8 fp16 = 40 KB ----
    __shared__ __align__(16) _Float16 WL[5 * 8 * 64 * 8];
    __shared__ float sb0[144], sb1[144], sb2[144], sw0[144];

    {
        const float* srcs[5] = {Whh0, Wih1, Whh1, Wih2, Whh2};
#pragma unroll
        for (int w = 0; w < 5; ++w)
#pragma unroll
            for (int m = 0; m < 8; ++m) {
                const int rowA = qa * 32 + 8 * gp + m;
                f16x8 f = loadrow8(srcs[w] + rowA * 32 + 8 * g);
                *reinterpret_cast<f16x8*>(&WL[((w * 8 + m) * 64 + l) * 8]) = f;
            }
    }
    for (int e = l; e < 128; e += 64) {
        const int u = e >> 2, r = e & 3;
        const int idx = (u + (u >> 3)) * 4 + r;   // staggered, conflict-free
        sb0[idx] = bih0[r * 32 + u] + bhh0[r * 32 + u];
        sb1[idx] = bih1[r * 32 + u] + bhh1[r * 32 + u];
        sb2[idx] = bih2[r * 32 + u] + bhh2[r * 32 + u];
        sw0[idx] = Wih0[r * 32 + u];
    }
    __syncthreads();

    float wfc[8];
#pragma unroll
    for (int m = 0; m < 8; ++m) wfc[m] = Wfc[8 * g + m];
    const float bfc0 = bfc[0];

    f16x8 hb0 = {0, 0, 0, 0, 0, 0, 0, 0};
    f16x8 hb1 = {0, 0, 0, 0, 0, 0, 0, 0};
    f16x8 hb2 = {0, 0, 0, 0, 0, 0, 0, 0};
    float c0[8], c1[8], c2[8];
#pragma unroll
    for (int m = 0; m < 8; ++m) { c0[m] = 0.f; c1[m] = 0.f; c2[m] = 0.f; }

    unsigned wq = 0;                  // laundered each iter -> LDS reads
                                      // cannot be hoisted out of the loop
    float xv = x[b0 + b];
    for (int t = 0; t < T_STEPS; ++t) {
        asm volatile("" : "+v"(wq));
        const _Float16* WB = &WL[wq + l * 8];

        const int tn = (t + 1 < T_STEPS) ? t + 1 : t;
        const float xn = x[tn * NBATCH + b0 + b];

        f32x4 acc[8];
        float hn[8];
        f16x8 fi[8], fh[8];

        // ================= layer 0: gates = Whh0 @ h0 (+ Wih0*x + b) =======
#pragma unroll
        for (int m = 0; m < 8; ++m)
            fi[m] = *reinterpret_cast<const f16x8*>(WB + (0 * 8 + m) * 512);
#pragma unroll
        for (int m = 0; m < 8; ++m) {
            f32x4 z = {0.f, 0.f, 0.f, 0.f};
            acc[m] = __builtin_amdgcn_mfma_f32_16x16x32_f16(fi[m], hb0, z, 0, 0, 0);
        }
#pragma unroll
        for (int m = 0; m < 8; ++m) {
            const float4 bb = *reinterpret_cast<const float4*>(&sb0[(9 * g + m) * 4]);
            const float4 w0 = *reinterpret_cast<const float4*>(&sw0[(9 * g + m) * 4]);
            const float gi = fmaf(w0.x, xv, acc[m][0] + bb.x);
            const float gf = fmaf(w0.y, xv, acc[m][1] + bb.y);
            const float gg = fmaf(w0.z, xv, acc[m][2] + bb.z);
            const float go = fmaf(w0.w, xv, acc[m][3] + bb.w);
            const float ii = sigm(gi), ff = sigm(gf);
            const float gz = tanh_fast(gg), oo = sigm(go);
            c0[m] = fmaf(ff, c0[m], ii * gz);
            hn[m] = oo * tanh_fast(c0[m]);
        }
#pragma unroll
        for (int m = 0; m < 8; ++m) hb0[m] = (_Float16)hn[m];

        // ================= layer 1: gates = Wih1 @ h0new + Whh1 @ h1old ====
#pragma unroll
        for (int m = 0; m < 8; ++m) {
            fi[m] = *reinterpret_cast<const f16x8*>(WB + (1 * 8 + m) * 512);
            fh[m] = *reinterpret_cast<const f16x8*>(WB + (2 * 8 + m) * 512);
        }
#pragma unroll
        for (int m = 0; m < 8; ++m) {
            f32x4 z = {0.f, 0.f, 0.f, 0.f};
            z      = __builtin_amdgcn_mfma_f32_16x16x32_f16(fi[m], hb0, z, 0, 0, 0);
            acc[m] = __builtin_amdgcn_mfma_f32_16x16x32_f16(fh[m], hb1, z, 0, 0, 0);
        }
#pragma unroll
        for (int m = 0; m < 8; ++m) {
            const float4 bb = *reinterpret_cast<const float4*>(&sb1[(9 * g + m) * 4]);
            const float gi = acc[m][0] + bb.x;
            const float gf = acc[m][1] + bb.y;
            const float gg = acc[m][2] + bb.z;
            const float go = acc[m][3] + bb.w;
            const float ii = sigm(gi), ff = sigm(gf);
            const float gz = tanh_fast(gg), oo = sigm(go);
            c1[m] = fmaf(ff, c1[m], ii * gz);
            hn[m] = oo * tanh_fast(c1[m]);
        }
#pragma unroll
        for (int m = 0; m < 8; ++m) hb1[m] = (_Float16)hn[m];

        // ================= layer 2: gates = Wih2 @ h1new + Whh2 @ h2old ====
#pragma unroll
        for (int m = 0; m < 8; ++m) {
            fi[m] = *reinterpret_cast<const f16x8*>(WB + (3 * 8 + m) * 512);
            fh[m] = *reinterpret_cast<const f16x8*>(WB + (4 * 8 + m) * 512);
        }
#pragma unroll
        for (int m = 0; m < 8; ++m) {
            f32x4 z = {0.f, 0.f, 0.f, 0.f};
            z      = __builtin_amdgcn_mfma_f32_16x16x32_f16(fi[m], hb1, z, 0, 0, 0);
            acc[m] = __builtin_amdgcn_mfma_f32_16x16x32_f16(fh[m], hb2, z, 0, 0, 0);
        }
#pragma unroll
        for (int m = 0; m < 8; ++m) {
            const float4 bb = *reinterpret_cast<const float4*>(&sb2[(9 * g + m) * 4]);
            const float gi = acc[m][0] + bb.x;
            const float gf = acc[m][1] + bb.y;
            const float gg = acc[m][2] + bb.z;
            const float go = acc[m][3] + bb.w;
            const float ii = sigm(gi), ff = sigm(gf);
            const float gz = tanh_fast(gg), oo = sigm(go);
            c2[m] = fmaf(ff, c2[m], ii * gz);
            hn[m] = oo * tanh_fast(c2[m]);
        }
#pragma unroll
        for (int m = 0; m < 8; ++m) hb2[m] = (_Float16)hn[m];

        // ================= fused FC: out[t][b] = Wfc @ h2 + bfc ============
        float v = 0.f;
#pragma unroll
        for (int m = 0; m < 8; ++m) v = fmaf(wfc[m], hn[m], v);
        v += __shfl_xor(v, 16);
        v += __shfl_xor(v, 32);
        if (l < 16) out[t * NBATCH + b0 + l] = v + bfc0;

        xv = xn;
    }
}

extern "C" void kernel_launch(void* const* d_in, const int* in_sizes, int n_in,
                              void* d_out, int out_size, void* d_ws, size_t ws_size,
                              hipStream_t stream)
{
    const float* x    = (const float*)d_in[0];
    const float* Wih0 = (const float*)d_in[1];
    const float* Whh0 = (const float*)d_in[2];
    const float* bih0 = (const float*)d_in[3];
    const float* bhh0 = (const float*)d_in[4];
    const float* Wih1 = (const float*)d_in[5];
    const float* Whh1 = (const float*)d_in[6];
    const float* bih1 = (const float*)d_in[7];
    const float* bhh1 = (const float*)d_in[8];
    const float* Wih2 = (const float*)d_in[9];
    const float* Whh2 = (const float*)d_in[10];
    const float* bih2 = (const float*)d_in[11];
    const float* bhh2 = (const float*)d_in[12];
    const float* Wfc  = (const float*)d_in[13];
    const float* bfc  = (const float*)d_in[14];
    float* out        = (float*)d_out;

    lstm3_mfma_kernel<<<dim3(NBATCH / 16), dim3(64), 0, stream>>>(
        x, Wih0, Whh0, bih0, bhh0,
        Wih1, Whh1, bih1, bhh1,
        Wih2, Whh2, bih2, bhh2,
        Wfc, bfc, out);
}

// Round 8
// 5586.883 us; speedup vs baseline: 1.3583x; 1.3583x over previous
//
#include <hip/hip_runtime.h>

#define T_STEPS 2048
#define NBATCH  1024

typedef _Float16 f16x8 __attribute__((ext_vector_type(8)));
typedef float    f32x4 __attribute__((ext_vector_type(4)));

__device__ __forceinline__ float sigm(float v) {
    float e = __builtin_amdgcn_exp2f(-1.442695040888963f * v);
    return __builtin_amdgcn_rcpf(1.0f + e);
}
__device__ __forceinline__ float tanh_fast(float v) {
    float e = __builtin_amdgcn_exp2f(2.885390081777927f * v);
    return fmaf(-2.0f, __builtin_amdgcn_rcpf(1.0f + e), 1.0f);
}

// load 8 consecutive fp32 -> 8 fp16 (RNE) fragment
__device__ __forceinline__ f16x8 loadrow8(const float* p) {
    float4 lo = *reinterpret_cast<const float4*>(p);
    float4 hi = *reinterpret_cast<const float4*>(p + 4);
    f16x8 r;
    r[0] = (_Float16)lo.x; r[1] = (_Float16)lo.y;
    r[2] = (_Float16)lo.z; r[3] = (_Float16)lo.w;
    r[4] = (_Float16)hi.x; r[5] = (_Float16)hi.y;
    r[6] = (_Float16)hi.z; r[7] = (_Float16)hi.w;
    return r;
}

// One block = one wave = 16 batch columns for all T steps.
// MFMA layout (verified R6): lane l, tile m holds i,f,g,o of unit 8*(l>>4)+m
// for batch l&15 in its 4 acc regs; the 8 per-tile h results ARE the lane's
// next B-frag elements -> zero cross-lane in the recurrence.
// SKEW-3 PIPELINE: iteration n computes L0(t=n), L1(t=n-1), L2(t=n-2) --
// mutually independent -> 3x ILP on the serial chain. All 40 MFMAs issue
// against start-of-iteration hb0/hb1/hb2; activations update states after.
__global__ __launch_bounds__(64, 1)
void lstm3_mfma_kernel(const float* __restrict__ x,
                       const float* __restrict__ Wih0, const float* __restrict__ Whh0,
                       const float* __restrict__ bih0, const float* __restrict__ bhh0,
                       const float* __restrict__ Wih1, const float* __restrict__ Whh1,
                       const float* __restrict__ bih1, const float* __restrict__ bhh1,
                       const float* __restrict__ Wih2, const float* __restrict__ Whh2,
                       const float* __restrict__ bih2, const float* __restrict__ bhh2,
                       const float* __restrict__ Wfc,  const float* __restrict__ bfc,
                       float* __restrict__ out)
{
    const int l  = threadIdx.x;       // 0..63
    const int g  = l >> 4;            // lane group (k-chunk / C row-group)
    const int b  = l & 15;            // batch column within tile
    const int qa = l & 3;             // gate index for A-row loads
    const int gp = (l & 15) >> 2;     // unit group for A-row loads
    const int b0 = blockIdx.x * 16;   // batch-tile base

    // ---- LDS: 5 matrices x 8 tiles x 64 lanes x 8 fp16 = 40 KB ----
    __shared__ __align__(16) _Float16 WL[5 * 8 * 64 * 8];
    __shared__ float sb0[144], sb1[144], sb2[144], sw0[144];

    {
        const float* srcs[5] = {Whh0, Wih1, Whh1, Wih2, Whh2};
#pragma unroll
        for (int w = 0; w < 5; ++w)
#pragma unroll
            for (int m = 0; m < 8; ++m) {
                const int rowA = qa * 32 + 8 * gp + m;
                f16x8 f = loadrow8(srcs[w] + rowA * 32 + 8 * g);
                *reinterpret_cast<f16x8*>(&WL[((w * 8 + m) * 64 + l) * 8]) = f;
            }
    }
    for (int e = l; e < 128; e += 64) {
        const int u = e >> 2, r = e & 3;
        const int idx = (u + (u >> 3)) * 4 + r;   // staggered, conflict-free
        sb0[idx] = bih0[r * 32 + u] + bhh0[r * 32 + u];
        sb1[idx] = bih1[r * 32 + u] + bhh1[r * 32 + u];
        sb2[idx] = bih2[r * 32 + u] + bhh2[r * 32 + u];
        sw0[idx] = Wih0[r * 32 + u];
    }
    __syncthreads();

    float wfc[8];
#pragma unroll
    for (int m = 0; m < 8; ++m) wfc[m] = Wfc[8 * g + m];
    const float bfc0 = bfc[0];

    f16x8 hb0 = {0, 0, 0, 0, 0, 0, 0, 0};
    f16x8 hb1 = {0, 0, 0, 0, 0, 0, 0, 0};
    f16x8 hb2 = {0, 0, 0, 0, 0, 0, 0, 0};
    float c0[8], c1[8], c2[8];
#pragma unroll
    for (int m = 0; m < 8; ++m) { c0[m] = 0.f; c1[m] = 0.f; c2[m] = 0.f; }

    unsigned wq = 0;                  // laundered -> LDS frag reads stay in-loop
    float xv = x[b0 + b];             // x[t=0]
    for (int t = 0; t < T_STEPS + 2; ++t) {
        asm volatile("" : "+v"(wq));
        const _Float16* WB = &WL[wq + l * 8];

        const int tn = (t + 1 < T_STEPS) ? t + 1 : T_STEPS - 1;
        const float xn = x[tn * NBATCH + b0 + b];

        // ======== MFMA block: all 40, on start-of-iteration states ========
        f32x4 acc0[8], acc1[8], acc2[8];
#pragma unroll
        for (int m = 0; m < 8; ++m) {
            f16x8 F0 = *reinterpret_cast<const f16x8*>(WB + (0 * 8 + m) * 512);
            f32x4 z = {0.f, 0.f, 0.f, 0.f};
            acc0[m] = __builtin_amdgcn_mfma_f32_16x16x32_f16(F0, hb0, z, 0, 0, 0);
        }
#pragma unroll
        for (int m = 0; m < 8; ++m) {
            f16x8 Fi = *reinterpret_cast<const f16x8*>(WB + (1 * 8 + m) * 512);
            f16x8 Fh = *reinterpret_cast<const f16x8*>(WB + (2 * 8 + m) * 512);
            f32x4 z = {0.f, 0.f, 0.f, 0.f};
            z       = __builtin_amdgcn_mfma_f32_16x16x32_f16(Fi, hb0, z, 0, 0, 0);
            acc1[m] = __builtin_amdgcn_mfma_f32_16x16x32_f16(Fh, hb1, z, 0, 0, 0);
        }
#pragma unroll
        for (int m = 0; m < 8; ++m) {
            f16x8 Fi = *reinterpret_cast<const f16x8*>(WB + (3 * 8 + m) * 512);
            f16x8 Fh = *reinterpret_cast<const f16x8*>(WB + (4 * 8 + m) * 512);
            f32x4 z = {0.f, 0.f, 0.f, 0.f};
            z       = __builtin_amdgcn_mfma_f32_16x16x32_f16(Fi, hb1, z, 0, 0, 0);
            acc2[m] = __builtin_amdgcn_mfma_f32_16x16x32_f16(Fh, hb2, z, 0, 0, 0);
        }

        // ======== L2 activation (t-2) + fused FC ========
        if (t >= 2) {
            float hn[8];
#pragma unroll
            for (int m = 0; m < 8; ++m) {
                const float4 bb = *reinterpret_cast<const float4*>(&sb2[(9 * g + m) * 4]);
                const float ii = sigm(acc2[m][0] + bb.x);
                const float ff = sigm(acc2[m][1] + bb.y);
                const float gz = tanh_fast(acc2[m][2] + bb.z);
                const float oo = sigm(acc2[m][3] + bb.w);
                c2[m] = fmaf(ff, c2[m], ii * gz);
                hn[m] = oo * tanh_fast(c2[m]);
            }
#pragma unroll
            for (int m = 0; m < 8; ++m) hb2[m] = (_Float16)hn[m];
            float v = 0.f;
#pragma unroll
            for (int m = 0; m < 8; ++m) v = fmaf(wfc[m], hn[m], v);
            v += __shfl_xor(v, 16);
            v += __shfl_xor(v, 32);
            if (l < 16) out[(t - 2) * NBATCH + b0 + l] = v + bfc0;
        }

        // ======== L1 activation (t-1) ========
        if (t >= 1 && t <= T_STEPS) {
            float hn[8];
#pragma unroll
            for (int m = 0; m < 8; ++m) {
                const float4 bb = *reinterpret_cast<const float4*>(&sb1[(9 * g + m) * 4]);
                const float ii = sigm(acc1[m][0] + bb.x);
                const float ff = sigm(acc1[m][1] + bb.y);
                const float gz = tanh_fast(acc1[m][2] + bb.z);
                const float oo = sigm(acc1[m][3] + bb.w);
                c1[m] = fmaf(ff, c1[m], ii * gz);
                hn[m] = oo * tanh_fast(c1[m]);
            }
#pragma unroll
            for (int m = 0; m < 8; ++m) hb1[m] = (_Float16)hn[m];
        }

        // ======== L0 activation (t) ========
        if (t < T_STEPS) {
            float hn[8];
#pragma unroll
            for (int m = 0; m < 8; ++m) {
                const float4 bb = *reinterpret_cast<const float4*>(&sb0[(9 * g + m) * 4]);
                const float4 w0 = *reinterpret_cast<const float4*>(&sw0[(9 * g + m) * 4]);
                const float ii = sigm(fmaf(w0.x, xv, acc0[m][0] + bb.x));
                const float ff = sigm(fmaf(w0.y, xv, acc0[m][1] + bb.y));
                const float gz = tanh_fast(fmaf(w0.z, xv, acc0[m][2] + bb.z));
                const float oo = sigm(fmaf(w0.w, xv, acc0[m][3] + bb.w));
                c0[m] = fmaf(ff, c0[m], ii * gz);
                hn[m] = oo * tanh_fast(c0[m]);
            }
#pragma unroll
            for (int m = 0; m < 8; ++m) hb0[m] = (_Float16)hn[m];
        }

        xv = xn;
    }
}

extern "C" void kernel_launch(void* const* d_in, const int* in_sizes, int n_in,
                              void* d_out, int out_size, void* d_ws, size_t ws_size,
                              hipStream_t stream)
{
    const float* x    = (const float*)d_in[0];
    const float* Wih0 = (const float*)d_in[1];
    const float* Whh0 = (const float*)d_in[2];
    const float* bih0 = (const float*)d_in[3];
    const float* bhh0 = (const float*)d_in[4];
    const float* Wih1 = (const float*)d_in[5];
    const float* Whh1 = (const float*)d_in[6];
    const float* bih1 = (const float*)d_in[7];
    const float* bhh1 = (const float*)d_in[8];
    const float* Wih2 = (const float*)d_in[9];
    const float* Whh2 = (const float*)d_in[10];
    const float* bih2 = (const float*)d_in[11];
    const float* bhh2 = (const float*)d_in[12];
    const float* Wfc  = (const float*)d_in[13];
    const float* bfc  = (const float*)d_in[14];
    float* out        = (float*)d_out;

    lstm3_mfma_kernel<<<dim3(NBATCH / 16), dim3(64), 0, stream>>>(
        x, Wih0, Whh0, bih0, bhh0,
        Wih1, Whh1, bih1, bhh1,
        Wih2, Whh2, bih2, bhh2,
        Wfc, bfc, out);
}

// Round 9
// 2041.518 us; speedup vs baseline: 3.7173x; 2.7366x over previous
//
#include <hip/hip_runtime.h>

#define T_STEPS 2048
#define NBATCH  1024

typedef _Float16 f16x8 __attribute__((ext_vector_type(8)));
typedef float    f32x4 __attribute__((ext_vector_type(4)));

__device__ __forceinline__ float sigm(float v) {
    float e = __builtin_amdgcn_exp2f(-1.442695040888963f * v);
    return __builtin_amdgcn_rcpf(1.0f + e);
}
__device__ __forceinline__ float tanh_fast(float v) {
    float e = __builtin_amdgcn_exp2f(2.885390081777927f * v);
    return fmaf(-2.0f, __builtin_amdgcn_rcpf(1.0f + e), 1.0f);
}

// load 8 consecutive fp32 -> 8 fp16 (RNE) fragment
__device__ __forceinline__ f16x8 loadrow8(const float* p) {
    float4 lo = *reinterpret_cast<const float4*>(p);
    float4 hi = *reinterpret_cast<const float4*>(p + 4);
    f16x8 r;
    r[0] = (_Float16)lo.x; r[1] = (_Float16)lo.y;
    r[2] = (_Float16)lo.z; r[3] = (_Float16)lo.w;
    r[4] = (_Float16)hi.x; r[5] = (_Float16)hi.y;
    r[6] = (_Float16)hi.z; r[7] = (_Float16)hi.w;
    return r;
}

// 3 waves per block, one LSTM layer per wave, 16 batch columns per block.
// MFMA layout (verified R6): lane l, tile m holds i,f,g,o of unit 8*(l>>4)+m
// for batch l&15; the lane's 8 per-tile h results ARE its next B-fragment ->
// the h handoff between waves is a lane-identity f16x8 copy through LDS.
// Skew: at iter n, wave0 computes L0(t=n), wave1 L1(t=n-1), wave2 L2(t=n-2).
// Triple-buffered handoff slots + one __syncthreads per iteration.
__global__ __launch_bounds__(192, 1)
void lstm3_mfma_kernel(const float* __restrict__ x,
                       const float* __restrict__ Wih0, const float* __restrict__ Whh0,
                       const float* __restrict__ bih0, const float* __restrict__ bhh0,
                       const float* __restrict__ Wih1, const float* __restrict__ Whh1,
                       const float* __restrict__ bih1, const float* __restrict__ bhh1,
                       const float* __restrict__ Wih2, const float* __restrict__ Whh2,
                       const float* __restrict__ bih2, const float* __restrict__ bhh2,
                       const float* __restrict__ Wfc,  const float* __restrict__ bfc,
                       float* __restrict__ out)
{
    const int tid = threadIdx.x;
    const int wid = tid >> 6;         // 0,1,2 = layer
    const int l   = tid & 63;         // lane
    const int g   = l >> 4;           // lane group (k-chunk / C row-group)
    const int b   = l & 15;           // batch column within tile
    const int qa  = l & 3;            // gate index for A-row loads
    const int gp  = (l & 15) >> 2;    // unit group for A-row loads
    const int b0  = blockIdx.x * 16;  // batch-tile base

    // ---- LDS ----
    __shared__ __align__(16) _Float16 WL[5 * 8 * 64 * 8];   // 40 KB weights
    __shared__ __align__(16) f16x8 hH0[3][64];              // h0 handoff
    __shared__ __align__(16) f16x8 hH1[3][64];              // h1 handoff
    __shared__ float sb0[144], sb1[144], sb2[144], sw0[144];

    // stage weights: wave w stages its own layer's matrices
    {
        const int rowA = qa * 32 + 8 * gp;
        if (wid == 0) {
#pragma unroll
            for (int m = 0; m < 8; ++m)
                *reinterpret_cast<f16x8*>(&WL[((0 * 8 + m) * 64 + l) * 8]) =
                    loadrow8(Whh0 + (rowA + m) * 32 + 8 * g);
        } else if (wid == 1) {
#pragma unroll
            for (int m = 0; m < 8; ++m) {
                *reinterpret_cast<f16x8*>(&WL[((1 * 8 + m) * 64 + l) * 8]) =
                    loadrow8(Wih1 + (rowA + m) * 32 + 8 * g);
                *reinterpret_cast<f16x8*>(&WL[((2 * 8 + m) * 64 + l) * 8]) =
                    loadrow8(Whh1 + (rowA + m) * 32 + 8 * g);
            }
        } else {
#pragma unroll
            for (int m = 0; m < 8; ++m) {
                *reinterpret_cast<f16x8*>(&WL[((3 * 8 + m) * 64 + l) * 8]) =
                    loadrow8(Wih2 + (rowA + m) * 32 + 8 * g);
                *reinterpret_cast<f16x8*>(&WL[((4 * 8 + m) * 64 + l) * 8]) =
                    loadrow8(Whh2 + (rowA + m) * 32 + 8 * g);
            }
        }
    }
    for (int e = tid; e < 128; e += 192) {
        const int u = e >> 2, r = e & 3;
        const int idx = (u + (u >> 3)) * 4 + r;   // staggered, conflict-free
        sb0[idx] = bih0[r * 32 + u] + bhh0[r * 32 + u];
        sb1[idx] = bih1[r * 32 + u] + bhh1[r * 32 + u];
        sb2[idx] = bih2[r * 32 + u] + bhh2[r * 32 + u];
        sw0[idx] = Wih0[r * 32 + u];
    }
    {   // zero-init handoff slots (slot indexing at n=0 reads slot 2: must be 0)
        f16x8 zz = {0, 0, 0, 0, 0, 0, 0, 0};
        if (wid == 0) { hH0[0][l] = zz; hH0[1][l] = zz; hH0[2][l] = zz; }
        if (wid == 1) { hH1[0][l] = zz; hH1[1][l] = zz; hH1[2][l] = zz; }
    }
    __syncthreads();

    float wfc[8];
#pragma unroll
    for (int m = 0; m < 8; ++m) wfc[m] = Wfc[8 * g + m];
    const float bfc0 = bfc[0];

    f16x8 hself = {0, 0, 0, 0, 0, 0, 0, 0};   // wave0: h0; wave1: h1; wave2: h2
    float cst[8];
#pragma unroll
    for (int m = 0; m < 8; ++m) cst[m] = 0.f;

    unsigned wq = 0;                  // laundered -> LDS frag reads stay in-loop
    float xv = (wid == 0) ? x[b0 + b] : 0.f;

    int sw = 0, sr = 2;               // write slot n%3, read slot (n+2)%3
    for (int n = 0; n < T_STEPS + 2; ++n) {
        asm volatile("" : "+v"(wq));
        const _Float16* WB = &WL[wq + l * 8];

        if (wid == 0) {
            // ================= L0(t=n): gates = Whh0 @ h0 + Wih0*x + b ====
            if (n < T_STEPS) {
                const int tn = (n + 1 < T_STEPS) ? n + 1 : T_STEPS - 1;
                const float xn = x[tn * NBATCH + b0 + b];
                f32x4 acc[8];
#pragma unroll
                for (int m = 0; m < 8; ++m) {
                    f16x8 F = *reinterpret_cast<const f16x8*>(WB + (0 * 8 + m) * 512);
                    f32x4 z = {0.f, 0.f, 0.f, 0.f};
                    acc[m] = __builtin_amdgcn_mfma_f32_16x16x32_f16(F, hself, z, 0, 0, 0);
                }
                float hn[8];
#pragma unroll
                for (int m = 0; m < 8; ++m) {
                    const float4 bb = *reinterpret_cast<const float4*>(&sb0[(9 * g + m) * 4]);
                    const float4 w0 = *reinterpret_cast<const float4*>(&sw0[(9 * g + m) * 4]);
                    const float ii = sigm(fmaf(w0.x, xv, acc[m][0] + bb.x));
                    const float ff = sigm(fmaf(w0.y, xv, acc[m][1] + bb.y));
                    const float gz = tanh_fast(fmaf(w0.z, xv, acc[m][2] + bb.z));
                    const float oo = sigm(fmaf(w0.w, xv, acc[m][3] + bb.w));
                    cst[m] = fmaf(ff, cst[m], ii * gz);
                    hn[m]  = oo * tanh_fast(cst[m]);
                }
#pragma unroll
                for (int m = 0; m < 8; ++m) hself[m] = (_Float16)hn[m];
                hH0[sw][l] = hself;
                xv = xn;
            }
        } else if (wid == 1) {
            // ========= L1(t=n-1): gates = Wih1 @ h0(t=n-1) + Whh1 @ h1 ====
            if (n >= 1 && n <= T_STEPS) {
                f16x8 hb0 = hH0[sr][l];
                f32x4 acc[8];
#pragma unroll
                for (int m = 0; m < 8; ++m) {
                    f16x8 Fi = *reinterpret_cast<const f16x8*>(WB + (1 * 8 + m) * 512);
                    f16x8 Fh = *reinterpret_cast<const f16x8*>(WB + (2 * 8 + m) * 512);
                    f32x4 z = {0.f, 0.f, 0.f, 0.f};
                    z      = __builtin_amdgcn_mfma_f32_16x16x32_f16(Fi, hb0, z, 0, 0, 0);
                    acc[m] = __builtin_amdgcn_mfma_f32_16x16x32_f16(Fh, hself, z, 0, 0, 0);
                }
                float hn[8];
#pragma unroll
                for (int m = 0; m < 8; ++m) {
                    const float4 bb = *reinterpret_cast<const float4*>(&sb1[(9 * g + m) * 4]);
                    const float ii = sigm(acc[m][0] + bb.x);
                    const float ff = sigm(acc[m][1] + bb.y);
                    const float gz = tanh_fast(acc[m][2] + bb.z);
                    const float oo = sigm(acc[m][3] + bb.w);
                    cst[m] = fmaf(ff, cst[m], ii * gz);
                    hn[m]  = oo * tanh_fast(cst[m]);
                }
#pragma unroll
                for (int m = 0; m < 8; ++m) hself[m] = (_Float16)hn[m];
                hH1[sw][l] = hself;
            }
        } else {
            // ==== L2(t=n-2): gates = Wih2 @ h1(t=n-2) + Whh2 @ h2; FC =====
            if (n >= 2) {
                f16x8 hb1 = hH1[sr][l];
                f32x4 acc[8];
#pragma unroll
                for (int m = 0; m < 8; ++m) {
                    f16x8 Fi = *reinterpret_cast<const f16x8*>(WB + (3 * 8 + m) * 512);
                    f16x8 Fh = *reinterpret_cast<const f16x8*>(WB + (4 * 8 + m) * 512);
                    f32x4 z = {0.f, 0.f, 0.f, 0.f};
                    z      = __builtin_amdgcn_mfma_f32_16x16x32_f16(Fi, hb1, z, 0, 0, 0);
                    acc[m] = __builtin_amdgcn_mfma_f32_16x16x32_f16(Fh, hself, z, 0, 0, 0);
                }
                float hn[8];
#pragma unroll
                for (int m = 0; m < 8; ++m) {
                    const float4 bb = *reinterpret_cast<const float4*>(&sb2[(9 * g + m) * 4]);
                    const float ii = sigm(acc[m][0] + bb.x);
                    const float ff = sigm(acc[m][1] + bb.y);
                    const float gz = tanh_fast(acc[m][2] + bb.z);
                    const float oo = sigm(acc[m][3] + bb.w);
                    cst[m] = fmaf(ff, cst[m], ii * gz);
                    hn[m]  = oo * tanh_fast(cst[m]);
                }
#pragma unroll
                for (int m = 0; m < 8; ++m) hself[m] = (_Float16)hn[m];
                float v = 0.f;
#pragma unroll
                for (int m = 0; m < 8; ++m) v = fmaf(wfc[m], hn[m], v);
                v += __shfl_xor(v, 16);
                v += __shfl_xor(v, 32);
                if (l < 16) out[(n - 2) * NBATCH + b0 + l] = v + bfc0;
            }
        }

        __syncthreads();              // one barrier per iteration: slot s is
                                      // rewritten >= 2 barriers after its read
        sr = sw; sw = (sw == 2) ? 0 : sw + 1;
    }
}

extern "C" void kernel_launch(void* const* d_in, const int* in_sizes, int n_in,
                              void* d_out, int out_size, void* d_ws, size_t ws_size,
                              hipStream_t stream)
{
    const float* x    = (const float*)d_in[0];
    const float* Wih0 = (const float*)d_in[1];
    const float* Whh0 = (const float*)d_in[2];
    const float* bih0 = (const float*)d_in[3];
    const float* bhh0 = (const float*)d_in[4];
    const float* Wih1 = (const float*)d_in[5];
    const float* Whh1 = (const float*)d_in[6];
    const float* bih1 = (const float*)d_in[7];
    const float* bhh1 = (const float*)d_in[8];
    const float* Wih2 = (const float*)d_in[9];
    const float* Whh2 = (const float*)d_in[10];
    const float* bih2 = (const float*)d_in[11];
    const float* bhh2 = (const float*)d_in[12];
    const float* Wfc  = (const float*)d_in[13];
    const float* bfc  = (const float*)d_in[14];
    float* out        = (float*)d_out;

    lstm3_mfma_kernel<<<dim3(NBATCH / 16), dim3(192), 0, stream>>>(
        x, Wih0, Whh0, bih0, bhh0,
        Wih1, Whh1, bih1, bhh1,
        Wih2, Whh2, bih2, bhh2,
        Wfc, bfc, out);
}

// Round 11
// 1713.496 us; speedup vs baseline: 4.4289x; 1.1914x over previous
//
#include <hip/hip_runtime.h>

#define T_STEPS 2048
#define NBATCH  1024
#define L2E     1.442695040888963f

typedef _Float16 f16x8 __attribute__((ext_vector_type(8)));
typedef float    f32x4 __attribute__((ext_vector_type(4)));

// pack 2 floats -> 2 fp16 (RTZ) as one u32
__device__ __forceinline__ unsigned pk2(float a, float b) {
    auto v = __builtin_amdgcn_cvt_pkrtz(a, b);
    return __builtin_bit_cast(unsigned, v);
}

// load 8 consecutive fp32 -> 8 fp16 (RNE) fragment
__device__ __forceinline__ f16x8 loadrow8(const float* p) {
    float4 lo = *reinterpret_cast<const float4*>(p);
    float4 hi = *reinterpret_cast<const float4*>(p + 4);
    f16x8 r;
    r[0] = (_Float16)lo.x; r[1] = (_Float16)lo.y;
    r[2] = (_Float16)lo.z; r[3] = (_Float16)lo.w;
    r[4] = (_Float16)hi.x; r[5] = (_Float16)hi.y;
    r[6] = (_Float16)hi.z; r[7] = (_Float16)hi.w;
    return r;
}
__device__ __forceinline__ float rcp1p(float e) {   // 1/(1+e)
    return __builtin_amdgcn_rcpf(1.0f + e);
}

// 6 waves per block: (layer, half) with half = m-tiles {0..3} or {4..7}.
// 16 batch columns per block. MFMA layout (verified R6): lane l, tile m holds
// i,f,g,o of unit 8*(l>>4)+m for batch l&15; element e of the lane's B-frag
// is its tile-e h output -> full frag = concat of the two halves' 8B packs.
// Skew: at iter n, L0 computes t=n, L1 t=n-1, L2 t=n-2. All handoffs are
// "written iter n-1, read iter n" from 3-slot rotating LDS; 1 barrier/iter.
__global__ __launch_bounds__(384, 1)
void lstm3_ws6_kernel(const float* __restrict__ x,
                      const float* __restrict__ Wih0, const float* __restrict__ Whh0,
                      const float* __restrict__ bih0, const float* __restrict__ bhh0,
                      const float* __restrict__ Wih1, const float* __restrict__ Whh1,
                      const float* __restrict__ bih1, const float* __restrict__ bhh1,
                      const float* __restrict__ Wih2, const float* __restrict__ Whh2,
                      const float* __restrict__ bih2, const float* __restrict__ bhh2,
                      const float* __restrict__ Wfc,  const float* __restrict__ bfc,
                      float* __restrict__ out)
{
    const int tid  = threadIdx.x;
    const int wid  = tid >> 6;        // 0..5
    const int lay  = wid >> 1;        // layer 0..2
    const int half = wid & 1;         // m-half
    const int l    = tid & 63;
    const int g    = l >> 4;          // lane group (k-chunk / C row-group)
    const int b    = l & 15;          // batch column
    const int qa   = l & 3;           // gate index for A-row loads
    const int gp   = (l & 15) >> 2;   // unit group for A-row loads
    const int b0   = blockIdx.x * 16;
    const int m0   = half * 4;        // this wave's m-tile base

    __shared__ __align__(16) _Float16 WL[5 * 8 * 64 * 8];   // 40 KB weights
    __shared__ __align__(16) f16x8 hF[3][3][64];            // [slot][layer][lane]
    __shared__ float sb[4][144];                            // b0,b1,b2,w0 staggered
    __shared__ float FCpart[3][16];

    // ---- stage this wave's weight tiles ----
    {
        const int rowA = qa * 32 + 8 * gp + m0;
        if (lay == 0) {
#pragma unroll
            for (int mm = 0; mm < 4; ++mm)
                *reinterpret_cast<f16x8*>(&WL[((0 * 8 + m0 + mm) * 64 + l) * 8]) =
                    loadrow8(Whh0 + (rowA + mm) * 32 + 8 * g);
        } else if (lay == 1) {
#pragma unroll
            for (int mm = 0; mm < 4; ++mm) {
                *reinterpret_cast<f16x8*>(&WL[((1 * 8 + m0 + mm) * 64 + l) * 8]) =
                    loadrow8(Wih1 + (rowA + mm) * 32 + 8 * g);
                *reinterpret_cast<f16x8*>(&WL[((2 * 8 + m0 + mm) * 64 + l) * 8]) =
                    loadrow8(Whh1 + (rowA + mm) * 32 + 8 * g);
            }
        } else {
#pragma unroll
            for (int mm = 0; mm < 4; ++mm) {
                *reinterpret_cast<f16x8*>(&WL[((3 * 8 + m0 + mm) * 64 + l) * 8]) =
                    loadrow8(Wih2 + (rowA + mm) * 32 + 8 * g);
                *reinterpret_cast<f16x8*>(&WL[((4 * 8 + m0 + mm) * 64 + l) * 8]) =
                    loadrow8(Whh2 + (rowA + mm) * 32 + 8 * g);
            }
        }
    }
    for (int e = tid; e < 128; e += 384) {
        const int u = e >> 2, r = e & 3;
        const int idx = (u + (u >> 3)) * 4 + r;   // staggered
        sb[0][idx] = bih0[r * 32 + u] + bhh0[r * 32 + u];
        sb[1][idx] = bih1[r * 32 + u] + bhh1[r * 32 + u];
        sb[2][idx] = bih2[r * 32 + u] + bhh2[r * 32 + u];
        sb[3][idx] = Wih0[r * 32 + u];
    }
    if (wid < 3) {                    // zero all h slots (reads at n<3 see 0)
        f16x8 zz = {0, 0, 0, 0, 0, 0, 0, 0};
        hF[0][wid][l] = zz; hF[1][wid][l] = zz; hF[2][wid][l] = zz;
    }
    __syncthreads();

    // ---- hoist per-lane constants into registers (pre-scaled by log2e) ----
    float4 bs[4], w0s[4];
#pragma unroll
    for (int mm = 0; mm < 4; ++mm) {
        const float4 bb = *reinterpret_cast<const float4*>(&sb[lay][(9 * g + m0 + mm) * 4]);
        bs[mm] = make_float4(-L2E * bb.x, -L2E * bb.y, 2.f * L2E * bb.z, -L2E * bb.w);
    }
    if (lay == 0) {
#pragma unroll
        for (int mm = 0; mm < 4; ++mm) {
            const float4 w0 = *reinterpret_cast<const float4*>(&sb[3][(9 * g + m0 + mm) * 4]);
            w0s[mm] = make_float4(-L2E * w0.x, -L2E * w0.y, 2.f * L2E * w0.z, -L2E * w0.w);
        }
    }
    float wfc_r[4];
    if (lay == 2) {
#pragma unroll
        for (int mm = 0; mm < 4; ++mm) wfc_r[mm] = Wfc[8 * g + m0 + mm];
    }
    const float bfc0 = bfc[0];

    float cst[4] = {0.f, 0.f, 0.f, 0.f};
    float vprev = 0.f;
    float xv = (lay == 0) ? x[b0 + b] : 0.f;

    int sw = 0, sr = 2;
    for (int n = 0; n < T_STEPS + 3; ++n) {
        if (lay == 0) {
            // ============ L0(t=n): gates = Whh0 @ h0 + Wih0*x + b =========
            if (n < T_STEPS) {
                const int tn = (n + 1 < T_STEPS) ? n + 1 : T_STEPS - 1;
                const float xn = x[tn * NBATCH + b0 + b];
                const f16x8 hb0 = hF[sr][0][l];
                f32x4 acc[4];
#pragma unroll
                for (int mm = 0; mm < 4; ++mm) {
                    const f16x8 F = *reinterpret_cast<const f16x8*>(
                        &WL[((0 * 8 + m0 + mm) * 64 + l) * 8]);
                    f32x4 z = {0.f, 0.f, 0.f, 0.f};
                    acc[mm] = __builtin_amdgcn_mfma_f32_16x16x32_f16(F, hb0, z, 0, 0, 0);
                }
                float hn[4];
#pragma unroll
                for (int mm = 0; mm < 4; ++mm) {
                    const float ti = fmaf(w0s[mm].x, xv, fmaf(-L2E,      acc[mm][0], bs[mm].x));
                    const float tf = fmaf(w0s[mm].y, xv, fmaf(-L2E,      acc[mm][1], bs[mm].y));
                    const float tg = fmaf(w0s[mm].z, xv, fmaf(2.f * L2E, acc[mm][2], bs[mm].z));
                    const float to = fmaf(w0s[mm].w, xv, fmaf(-L2E,      acc[mm][3], bs[mm].w));
                    const float ii = rcp1p(__builtin_amdgcn_exp2f(ti));
                    const float ff = rcp1p(__builtin_amdgcn_exp2f(tf));
                    const float gz = fmaf(-2.f, rcp1p(__builtin_amdgcn_exp2f(tg)), 1.f);
                    const float oo = rcp1p(__builtin_amdgcn_exp2f(to));
                    cst[mm] = fmaf(ff, cst[mm], ii * gz);
                    const float ec = __builtin_amdgcn_exp2f(2.f * L2E * cst[mm]);
                    hn[mm] = oo * fmaf(-2.f, rcp1p(ec), 1.f);
                }
                uint2 pk;
                pk.x = pk2(hn[0], hn[1]);
                pk.y = pk2(hn[2], hn[3]);
                *(reinterpret_cast<uint2*>(&hF[sw][0][l]) + half) = pk;
                xv = xn;
            }
        } else if (lay == 1) {
            // ===== L1(t=n-1): gates = Wih1 @ h0(n-1) + Whh1 @ h1(n-2) =====
            if (n >= 1 && n <= T_STEPS) {
                const f16x8 hb0 = hF[sr][0][l];
                const f16x8 hb1 = hF[sr][1][l];
                f32x4 acc[4];
#pragma unroll
                for (int mm = 0; mm < 4; ++mm) {
                    const f16x8 Fi = *reinterpret_cast<const f16x8*>(
                        &WL[((1 * 8 + m0 + mm) * 64 + l) * 8]);
                    const f16x8 Fh = *reinterpret_cast<const f16x8*>(
                        &WL[((2 * 8 + m0 + mm) * 64 + l) * 8]);
                    f32x4 z = {0.f, 0.f, 0.f, 0.f};
                    z       = __builtin_amdgcn_mfma_f32_16x16x32_f16(Fi, hb0, z, 0, 0, 0);
                    acc[mm] = __builtin_amdgcn_mfma_f32_16x16x32_f16(Fh, hb1, z, 0, 0, 0);
                }
                float hn[4];
#pragma unroll
                for (int mm = 0; mm < 4; ++mm) {
                    const float ti = fmaf(-L2E,      acc[mm][0], bs[mm].x);
                    const float tf = fmaf(-L2E,      acc[mm][1], bs[mm].y);
                    const float tg = fmaf(2.f * L2E, acc[mm][2], bs[mm].z);
                    const float to = fmaf(-L2E,      acc[mm][3], bs[mm].w);
                    const float ii = rcp1p(__builtin_amdgcn_exp2f(ti));
                    const float ff = rcp1p(__builtin_amdgcn_exp2f(tf));
                    const float gz = fmaf(-2.f, rcp1p(__builtin_amdgcn_exp2f(tg)), 1.f);
                    const float oo = rcp1p(__builtin_amdgcn_exp2f(to));
                    cst[mm] = fmaf(ff, cst[mm], ii * gz);
                    const float ec = __builtin_amdgcn_exp2f(2.f * L2E * cst[mm]);
                    hn[mm] = oo * fmaf(-2.f, rcp1p(ec), 1.f);
                }
                uint2 pk;
                pk.x = pk2(hn[0], hn[1]);
                pk.y = pk2(hn[2], hn[3]);
                *(reinterpret_cast<uint2*>(&hF[sw][1][l]) + half) = pk;
            }
        } else {
            // == L2(t=n-2): gates = Wih2 @ h1(n-2) + Whh2 @ h2(n-3); FC ====
            float vnew = 0.f;
            if (n >= 2 && n <= T_STEPS + 1) {
                const f16x8 hb1 = hF[sr][1][l];
                const f16x8 hb2 = hF[sr][2][l];
                f32x4 acc[4];
#pragma unroll
                for (int mm = 0; mm < 4; ++mm) {
                    const f16x8 Fi = *reinterpret_cast<const f16x8*>(
                        &WL[((3 * 8 + m0 + mm) * 64 + l) * 8]);
                    const f16x8 Fh = *reinterpret_cast<const f16x8*>(
                        &WL[((4 * 8 + m0 + mm) * 64 + l) * 8]);
                    f32x4 z = {0.f, 0.f, 0.f, 0.f};
                    z       = __builtin_amdgcn_mfma_f32_16x16x32_f16(Fi, hb1, z, 0, 0, 0);
                    acc[mm] = __builtin_amdgcn_mfma_f32_16x16x32_f16(Fh, hb2, z, 0, 0, 0);
                }
                float hn[4];
#pragma unroll
                for (int mm = 0; mm < 4; ++mm) {
                    const float ti = fmaf(-L2E,      acc[mm][0], bs[mm].x);
                    const float tf = fmaf(-L2E,      acc[mm][1], bs[mm].y);
                    const float tg = fmaf(2.f * L2E, acc[mm][2], bs[mm].z);
                    const float to = fmaf(-L2E,      acc[mm][3], bs[mm].w);
                    const float ii = rcp1p(__builtin_amdgcn_exp2f(ti));
                    const float ff = rcp1p(__builtin_amdgcn_exp2f(tf));
                    const float gz = fmaf(-2.f, rcp1p(__builtin_amdgcn_exp2f(tg)), 1.f);
                    const float oo = rcp1p(__builtin_amdgcn_exp2f(to));
                    cst[mm] = fmaf(ff, cst[mm], ii * gz);
                    const float ec = __builtin_amdgcn_exp2f(2.f * L2E * cst[mm]);
                    hn[mm] = oo * fmaf(-2.f, rcp1p(ec), 1.f);
                }
                uint2 pk;
                pk.x = pk2(hn[0], hn[1]);
                pk.y = pk2(hn[2], hn[3]);
                *(reinterpret_cast<uint2*>(&hF[sw][2][l]) + half) = pk;
                float v = 0.f;
#pragma unroll
                for (int mm = 0; mm < 4; ++mm) v = fmaf(wfc_r[mm], hn[mm], v);
                v += __shfl_xor(v, 16);
                v += __shfl_xor(v, 32);
                if (half == 0 && l < 16) FCpart[sw][l] = v;
                vnew = v;
            }
            if (half == 1) {
                if (n >= 3 && l < 16)
                    out[(n - 3) * NBATCH + b0 + l] = FCpart[sr][l] + vprev + bfc0;
                vprev = vnew;
            }
        }

        __syncthreads();              // slot sr is rewritten >=2 barriers later
        sr = sw; sw = (sw == 2) ? 0 : sw + 1;
    }
}

extern "C" void kernel_launch(void* const* d_in, const int* in_sizes, int n_in,
                              void* d_out, int out_size, void* d_ws, size_t ws_size,
                              hipStream_t stream)
{
    const float* x    = (const float*)d_in[0];
    const float* Wih0 = (const float*)d_in[1];
    const float* Whh0 = (const float*)d_in[2];
    const float* bih0 = (const float*)d_in[3];
    const float* bhh0 = (const float*)d_in[4];
    const float* Wih1 = (const float*)d_in[5];
    const float* Whh1 = (const float*)d_in[6];
    const float* bih1 = (const float*)d_in[7];
    const float* bhh1 = (const float*)d_in[8];
    const float* Wih2 = (const float*)d_in[9];
    const float* Whh2 = (const float*)d_in[10];
    const float* bih2 = (const float*)d_in[11];
    const float* bhh2 = (const float*)d_in[12];
    const float* Wfc  = (const float*)d_in[13];
    const float* bfc  = (const float*)d_in[14];
    float* out        = (float*)d_out;

    lstm3_ws6_kernel<<<dim3(NBATCH / 16), dim3(384), 0, stream>>>(
        x, Wih0, Whh0, bih0, bhh0,
        Wih1, Whh1, bih1, bhh1,
        Wih2, Whh2, bih2, bhh2,
        Wfc, bfc, out);
}

// Round 12
// 1687.223 us; speedup vs baseline: 4.4978x; 1.0156x over previous
//
#include <hip/hip_runtime.h>

#define T_STEPS 2048
#define NBATCH  1024
#define L2E     1.442695040888963f

typedef _Float16 f16x8 __attribute__((ext_vector_type(8)));
typedef float    f32x4 __attribute__((ext_vector_type(4)));

// pack 2 floats -> 2 fp16 (RTZ) as one u32
__device__ __forceinline__ unsigned pk2(float a, float b) {
    auto v = __builtin_amdgcn_cvt_pkrtz(a, b);
    return __builtin_bit_cast(unsigned, v);
}

// load 8 consecutive fp32 -> 8 fp16 (RNE) fragment
__device__ __forceinline__ f16x8 loadrow8(const float* p) {
    float4 lo = *reinterpret_cast<const float4*>(p);
    float4 hi = *reinterpret_cast<const float4*>(p + 4);
    f16x8 r;
    r[0] = (_Float16)lo.x; r[1] = (_Float16)lo.y;
    r[2] = (_Float16)lo.z; r[3] = (_Float16)lo.w;
    r[4] = (_Float16)hi.x; r[5] = (_Float16)hi.y;
    r[6] = (_Float16)hi.z; r[7] = (_Float16)hi.w;
    return r;
}
__device__ __forceinline__ float rcp1p(float e) {   // 1/(1+e)
    return __builtin_amdgcn_rcpf(1.0f + e);
}

// LDS-only barrier: drain LDS ops, sync, block LDS reordering across it.
// (No vmcnt drain -> global x-prefetch stays in flight across iterations.)
__device__ __forceinline__ void sync_lds() {
    asm volatile("s_waitcnt lgkmcnt(0)" ::: "memory");
    __builtin_amdgcn_s_barrier();
    asm volatile("" ::: "memory");
}

// Pin an f16x8 into VGPRs: asm output is opaque & non-rematerializable,
// so the value must stay register-resident for all later uses.
#define PIN8(f) do { uint4 _u = __builtin_bit_cast(uint4, (f));              \
    asm volatile("" : "+v"(_u.x), "+v"(_u.y), "+v"(_u.z), "+v"(_u.w));       \
    (f) = __builtin_bit_cast(f16x8, _u); } while (0)

// 6 waves per block: (layer, half), half = m-tiles {0..3} or {4..7};
// 16 batch columns per block. MFMA layout (verified R6): lane l, tile m holds
// i,f,g,o of unit 8*(l>>4)+m for batch l&15; element e of the lane's B-frag
// is its tile-e h output -> full frag = concat of the two halves' 8B packs.
// Weights live in REGISTERS (pinned); only h handoffs + FC partials in LDS.
// Skew: at iter n, L0 computes t=n, L1 t=n-1, L2 t=n-2; 3-slot rotation,
// one light (lgkm-only) barrier per iteration.
__global__ __launch_bounds__(384, 1)
void lstm3_ws6r_kernel(const float* __restrict__ x,
                       const float* __restrict__ Wih0, const float* __restrict__ Whh0,
                       const float* __restrict__ bih0, const float* __restrict__ bhh0,
                       const float* __restrict__ Wih1, const float* __restrict__ Whh1,
                       const float* __restrict__ bih1, const float* __restrict__ bhh1,
                       const float* __restrict__ Wih2, const float* __restrict__ Whh2,
                       const float* __restrict__ bih2, const float* __restrict__ bhh2,
                       const float* __restrict__ Wfc,  const float* __restrict__ bfc,
                       float* __restrict__ out)
{
    const int tid  = threadIdx.x;
    const int wid  = tid >> 6;        // 0..5
    const int lay  = wid >> 1;        // layer 0..2
    const int half = wid & 1;         // m-half
    const int l    = tid & 63;
    const int g    = l >> 4;          // lane group (k-chunk / C row-group)
    const int b    = l & 15;          // batch column
    const int qa   = l & 3;           // gate index for A-row loads
    const int gp   = (l & 15) >> 2;   // unit group for A-row loads
    const int b0   = blockIdx.x * 16;
    const int m0   = half * 4;        // this wave's m-tile base

    __shared__ __align__(16) f16x8 hF[3][3][64];   // [slot][layer][lane]
    __shared__ float FCpart[3][16];

    // ---- weight fragments -> registers (pinned) ----
    f16x8 Fi[4], Fh[4];
    {
        const int rowA = qa * 32 + 8 * gp + m0;
        const float* Pi = (lay == 1) ? Wih1 : ((lay == 2) ? Wih2 : nullptr);
        const float* Ph = (lay == 0) ? Whh0 : ((lay == 1) ? Whh1 : Whh2);
#pragma unroll
        for (int mm = 0; mm < 4; ++mm) {
            Fh[mm] = loadrow8(Ph + (rowA + mm) * 32 + 8 * g);
            PIN8(Fh[mm]);
        }
        if (lay != 0) {
#pragma unroll
            for (int mm = 0; mm < 4; ++mm) {
                Fi[mm] = loadrow8(Pi + (rowA + mm) * 32 + 8 * g);
                PIN8(Fi[mm]);
            }
        }
    }

    // ---- biases / Wih0 / Wfc -> registers (broadcast loads, pre-scaled) ----
    float4 bs[4], w0s[4];
    float wfc_r[4];
    {
        const float* BI = (lay == 0) ? bih0 : ((lay == 1) ? bih1 : bih2);
        const float* BH = (lay == 0) ? bhh0 : ((lay == 1) ? bhh1 : bhh2);
#pragma unroll
        for (int mm = 0; mm < 4; ++mm) {
            const int u = 8 * g + m0 + mm;
            const float bx = BI[u]      + BH[u];
            const float by = BI[u + 32] + BH[u + 32];
            const float bz = BI[u + 64] + BH[u + 64];
            const float bw = BI[u + 96] + BH[u + 96];
            bs[mm] = make_float4(-L2E * bx, -L2E * by, 2.f * L2E * bz, -L2E * bw);
            if (lay == 0)
                w0s[mm] = make_float4(-L2E * Wih0[u],      -L2E * Wih0[u + 32],
                                      2.f * L2E * Wih0[u + 64], -L2E * Wih0[u + 96]);
            if (lay == 2) wfc_r[mm] = Wfc[u];
        }
    }
    const float bfc0 = bfc[0];

    if (wid < 3) {                    // zero h slots (reads at n<3 see 0)
        f16x8 zz = {0, 0, 0, 0, 0, 0, 0, 0};
        hF[0][wid][l] = zz; hF[1][wid][l] = zz; hF[2][wid][l] = zz;
    }
    __syncthreads();

    float cst[4] = {0.f, 0.f, 0.f, 0.f};
    float vprev = 0.f;
    float xv = (lay == 0) ? x[b0 + b] : 0.f;

    int sw = 0, sr = 2;
    for (int n = 0; n < T_STEPS + 3; ++n) {
        if (lay == 0) {
            // ============ L0(t=n): gates = Whh0 @ h0 + Wih0*x + b =========
            if (n < T_STEPS) {
                const int tn = (n + 1 < T_STEPS) ? n + 1 : T_STEPS - 1;
                const float xn = x[tn * NBATCH + b0 + b];
                const f16x8 hb0 = hF[sr][0][l];
                f32x4 acc[4];
#pragma unroll
                for (int mm = 0; mm < 4; ++mm) {
                    f32x4 z = {0.f, 0.f, 0.f, 0.f};
                    acc[mm] = __builtin_amdgcn_mfma_f32_16x16x32_f16(Fh[mm], hb0, z, 0, 0, 0);
                }
                float hn[4];
#pragma unroll
                for (int mm = 0; mm < 4; ++mm) {
                    const float ti = fmaf(w0s[mm].x, xv, fmaf(-L2E,      acc[mm][0], bs[mm].x));
                    const float tf = fmaf(w0s[mm].y, xv, fmaf(-L2E,      acc[mm][1], bs[mm].y));
                    const float tg = fmaf(w0s[mm].z, xv, fmaf(2.f * L2E, acc[mm][2], bs[mm].z));
                    const float to = fmaf(w0s[mm].w, xv, fmaf(-L2E,      acc[mm][3], bs[mm].w));
                    const float ii = rcp1p(__builtin_amdgcn_exp2f(ti));
                    const float ff = rcp1p(__builtin_amdgcn_exp2f(tf));
                    const float gz = fmaf(-2.f, rcp1p(__builtin_amdgcn_exp2f(tg)), 1.f);
                    const float oo = rcp1p(__builtin_amdgcn_exp2f(to));
                    cst[mm] = fmaf(ff, cst[mm], ii * gz);
                    const float ec = __builtin_amdgcn_exp2f(2.f * L2E * cst[mm]);
                    hn[mm] = oo * fmaf(-2.f, rcp1p(ec), 1.f);
                }
                uint2 pk;
                pk.x = pk2(hn[0], hn[1]);
                pk.y = pk2(hn[2], hn[3]);
                *(reinterpret_cast<uint2*>(&hF[sw][0][l]) + half) = pk;
                xv = xn;
            }
        } else if (lay == 1) {
            // ===== L1(t=n-1): gates = Wih1 @ h0(n-1) + Whh1 @ h1(n-2) =====
            if (n >= 1 && n <= T_STEPS) {
                const f16x8 hb0 = hF[sr][0][l];
                const f16x8 hb1 = hF[sr][1][l];
                f32x4 acc[4];
#pragma unroll
                for (int mm = 0; mm < 4; ++mm) {
                    f32x4 z = {0.f, 0.f, 0.f, 0.f};
                    z       = __builtin_amdgcn_mfma_f32_16x16x32_f16(Fi[mm], hb0, z, 0, 0, 0);
                    acc[mm] = __builtin_amdgcn_mfma_f32_16x16x32_f16(Fh[mm], hb1, z, 0, 0, 0);
                }
                float hn[4];
#pragma unroll
                for (int mm = 0; mm < 4; ++mm) {
                    const float ti = fmaf(-L2E,      acc[mm][0], bs[mm].x);
                    const float tf = fmaf(-L2E,      acc[mm][1], bs[mm].y);
                    const float tg = fmaf(2.f * L2E, acc[mm][2], bs[mm].z);
                    const float to = fmaf(-L2E,      acc[mm][3], bs[mm].w);
                    const float ii = rcp1p(__builtin_amdgcn_exp2f(ti));
                    const float ff = rcp1p(__builtin_amdgcn_exp2f(tf));
                    const float gz = fmaf(-2.f, rcp1p(__builtin_amdgcn_exp2f(tg)), 1.f);
                    const float oo = rcp1p(__builtin_amdgcn_exp2f(to));
                    cst[mm] = fmaf(ff, cst[mm], ii * gz);
                    const float ec = __builtin_amdgcn_exp2f(2.f * L2E * cst[mm]);
                    hn[mm] = oo * fmaf(-2.f, rcp1p(ec), 1.f);
                }
                uint2 pk;
                pk.x = pk2(hn[0], hn[1]);
                pk.y = pk2(hn[2], hn[3]);
                *(reinterpret_cast<uint2*>(&hF[sw][1][l]) + half) = pk;
            }
        } else {
            // == L2(t=n-2): gates = Wih2 @ h1(n-2) + Whh2 @ h2(n-3); FC ====
            float vnew = 0.f;
            if (n >= 2 && n <= T_STEPS + 1) {
                const f16x8 hb1 = hF[sr][1][l];
                const f16x8 hb2 = hF[sr][2][l];
                f32x4 acc[4];
#pragma unroll
                for (int mm = 0; mm < 4; ++mm) {
                    f32x4 z = {0.f, 0.f, 0.f, 0.f};
                    z       = __builtin_amdgcn_mfma_f32_16x16x32_f16(Fi[mm], hb1, z, 0, 0, 0);
                    acc[mm] = __builtin_amdgcn_mfma_f32_16x16x32_f16(Fh[mm], hb2, z, 0, 0, 0);
                }
                float hn[4];
#pragma unroll
                for (int mm = 0; mm < 4; ++mm) {
                    const float ti = fmaf(-L2E,      acc[mm][0], bs[mm].x);
                    const float tf = fmaf(-L2E,      acc[mm][1], bs[mm].y);
                    const float tg = fmaf(2.f * L2E, acc[mm][2], bs[mm].z);
                    const float to = fmaf(-L2E,      acc[mm][3], bs[mm].w);
                    const float ii = rcp1p(__builtin_amdgcn_exp2f(ti));
                    const float ff = rcp1p(__builtin_amdgcn_exp2f(tf));
                    const float gz = fmaf(-2.f, rcp1p(__builtin_amdgcn_exp2f(tg)), 1.f);
                    const float oo = rcp1p(__builtin_amdgcn_exp2f(to));
                    cst[mm] = fmaf(ff, cst[mm], ii * gz);
                    const float ec = __builtin_amdgcn_exp2f(2.f * L2E * cst[mm]);
                    hn[mm] = oo * fmaf(-2.f, rcp1p(ec), 1.f);
                }
                uint2 pk;
                pk.x = pk2(hn[0], hn[1]);
                pk.y = pk2(hn[2], hn[3]);
                *(reinterpret_cast<uint2*>(&hF[sw][2][l]) + half) = pk;
                float v = 0.f;
#pragma unroll
                for (int mm = 0; mm < 4; ++mm) v = fmaf(wfc_r[mm], hn[mm], v);
                v += __shfl_xor(v, 16);
                v += __shfl_xor(v, 32);
                if (half == 0 && l < 16) FCpart[sw][l] = v;
                vnew = v;
            }
            if (half == 1) {
                if (n >= 3 && l < 16)
                    out[(n - 3) * NBATCH + b0 + l] = FCpart[sr][l] + vprev + bfc0;
                vprev = vnew;
            }
        }

        sync_lds();                   // lgkm-only barrier; slot sr is
                                      // rewritten >= 2 barriers after its read
        sr = sw; sw = (sw == 2) ? 0 : sw + 1;
    }
}

extern "C" void kernel_launch(void* const* d_in, const int* in_sizes, int n_in,
                              void* d_out, int out_size, void* d_ws, size_t ws_size,
                              hipStream_t stream)
{
    const float* x    = (const float*)d_in[0];
    const float* Wih0 = (const float*)d_in[1];
    const float* Whh0 = (const float*)d_in[2];
    const float* bih0 = (const float*)d_in[3];
    const float* bhh0 = (const float*)d_in[4];
    const float* Wih1 = (const float*)d_in[5];
    const float* Whh1 = (const float*)d_in[6];
    const float* bih1 = (const float*)d_in[7];
    const float* bhh1 = (const float*)d_in[8];
    const float* Wih2 = (const float*)d_in[9];
    const float* Whh2 = (const float*)d_in[10];
    const float* bih2 = (const float*)d_in[11];
    const float* bhh2 = (const float*)d_in[12];
    const float* Wfc  = (const float*)d_in[13];
    const float* bfc  = (const float*)d_in[14];
    float* out        = (float*)d_out;

    lstm3_ws6r_kernel<<<dim3(NBATCH / 16), dim3(384), 0, stream>>>(
        x, Wih0, Whh0, bih0, bhh0,
        Wih1, Whh1, bih1, bhh1,
        Wih2, Whh2, bih2, bhh2,
        Wfc, bfc, out);
}

// Round 13
// 1611.871 us; speedup vs baseline: 4.7081x; 1.0467x over previous
//
#include <hip/hip_runtime.h>

#define T_STEPS 2048
#define NBATCH  1024
#define L2E     1.442695040888963f

typedef _Float16 f16x8 __attribute__((ext_vector_type(8)));
typedef float    f32x4 __attribute__((ext_vector_type(4)));

// pack 2 floats -> 2 fp16 (RTZ) as one u32
__device__ __forceinline__ unsigned pk2(float a, float b) {
    auto v = __builtin_amdgcn_cvt_pkrtz(a, b);
    return __builtin_bit_cast(unsigned, v);
}

// load 8 consecutive fp32 -> 8 fp16 (RNE) fragment
__device__ __forceinline__ f16x8 loadrow8(const float* p) {
    float4 lo = *reinterpret_cast<const float4*>(p);
    float4 hi = *reinterpret_cast<const float4*>(p + 4);
    f16x8 r;
    r[0] = (_Float16)lo.x; r[1] = (_Float16)lo.y;
    r[2] = (_Float16)lo.z; r[3] = (_Float16)lo.w;
    r[4] = (_Float16)hi.x; r[5] = (_Float16)hi.y;
    r[6] = (_Float16)hi.z; r[7] = (_Float16)hi.w;
    return r;
}
__device__ __forceinline__ float rcp1p(float e) {   // 1/(1+e)
    return __builtin_amdgcn_rcpf(1.0f + e);
}

// LDS-only barrier (no vmcnt drain -> x prefetch stays in flight)
__device__ __forceinline__ void sync_lds() {
    asm volatile("s_waitcnt lgkmcnt(0)" ::: "memory");
    __builtin_amdgcn_s_barrier();
    asm volatile("" ::: "memory");
}

// Pin an f16x8 into VGPRs (opaque origin -> no remat/reload in the loop)
#define PIN8(f) do { uint4 _u = __builtin_bit_cast(uint4, (f));              \
    asm volatile("" : "+v"(_u.x), "+v"(_u.y), "+v"(_u.z), "+v"(_u.w));       \
    (f) = __builtin_bit_cast(f16x8, _u); } while (0)

// 3 waves per block, one LSTM layer per wave, 16 batch columns per block,
// TWO time-steps per barrier interval. MFMA layout (verified R6): lane l,
// tile m holds i,f,g,o of unit 8*(l>>4)+m for batch l&15; the lane's 8
// per-tile h results ARE its next B-fragment -> self-recurrent h stays in
// REGISTERS; only cross-layer handoffs (h0->L1, h1->L2) go through LDS.
// Skew: iter n = {L0: t=2n,2n+1 | L1: t=2n-2,2n-1 | L2: t=2n-4,2n-3 (+FC)}.
// 3-slot rotation, one light (lgkm-only) barrier per interval.
__global__ __launch_bounds__(192, 1)
void lstm3_ws3x2_kernel(const float* __restrict__ x,
                        const float* __restrict__ Wih0, const float* __restrict__ Whh0,
                        const float* __restrict__ bih0, const float* __restrict__ bhh0,
                        const float* __restrict__ Wih1, const float* __restrict__ Whh1,
                        const float* __restrict__ bih1, const float* __restrict__ bhh1,
                        const float* __restrict__ Wih2, const float* __restrict__ Whh2,
                        const float* __restrict__ bih2, const float* __restrict__ bhh2,
                        const float* __restrict__ Wfc,  const float* __restrict__ bfc,
                        float* __restrict__ out)
{
    const int tid = threadIdx.x;
    const int lay = tid >> 6;         // 0..2 = layer
    const int l   = tid & 63;
    const int g   = l >> 4;           // lane group (k-chunk / C row-group)
    const int b   = l & 15;           // batch column
    const int qa  = l & 3;            // gate index for A-row loads
    const int gp  = (l & 15) >> 2;    // unit group for A-row loads
    const int b0  = blockIdx.x * 16;

    __shared__ __align__(16) f16x8 hF0[3][2][64];   // h0 handoff [slot][step][lane]
    __shared__ __align__(16) f16x8 hF1[3][2][64];   // h1 handoff

    // ---- weight fragments -> registers (pinned) ----
    f16x8 Fi[8], Fh[8];
    {
        const int rowA = qa * 32 + 8 * gp;
        const float* Pi = (lay == 1) ? Wih1 : ((lay == 2) ? Wih2 : nullptr);
        const float* Ph = (lay == 0) ? Whh0 : ((lay == 1) ? Whh1 : Whh2);
#pragma unroll
        for (int m = 0; m < 8; ++m) {
            Fh[m] = loadrow8(Ph + (rowA + m) * 32 + 8 * g);
            PIN8(Fh[m]);
        }
        if (lay != 0) {
#pragma unroll
            for (int m = 0; m < 8; ++m) {
                Fi[m] = loadrow8(Pi + (rowA + m) * 32 + 8 * g);
                PIN8(Fi[m]);
            }
        }
    }

    // ---- biases / Wih0 / Wfc -> registers (pre-scaled by +/-log2e) ----
    float4 bs[8], w0s[8];
    float wfc_r[8];
    {
        const float* BI = (lay == 0) ? bih0 : ((lay == 1) ? bih1 : bih2);
        const float* BH = (lay == 0) ? bhh0 : ((lay == 1) ? bhh1 : bhh2);
#pragma unroll
        for (int m = 0; m < 8; ++m) {
            const int u = 8 * g + m;
            const float bx = BI[u]      + BH[u];
            const float by = BI[u + 32] + BH[u + 32];
            const float bz = BI[u + 64] + BH[u + 64];
            const float bw = BI[u + 96] + BH[u + 96];
            bs[m] = make_float4(-L2E * bx, -L2E * by, 2.f * L2E * bz, -L2E * bw);
            if (lay == 0)
                w0s[m] = make_float4(-L2E * Wih0[u],          -L2E * Wih0[u + 32],
                                     2.f * L2E * Wih0[u + 64], -L2E * Wih0[u + 96]);
            if (lay == 2) wfc_r[m] = Wfc[u];
        }
    }
    const float bfc0 = bfc[0];

    float cst[8];
#pragma unroll
    for (int m = 0; m < 8; ++m) cst[m] = 0.f;
    f16x8 hself = {0, 0, 0, 0, 0, 0, 0, 0};   // own layer's h (register!)

    float xvA = 0.f, xvB = 0.f;
    if (lay == 0) { xvA = x[b0 + b]; xvB = x[NBATCH + b0 + b]; }

    // one LSTM step on this wave's layer: acts on acc[8], updates cst/hself
#define ACT_STEP(USE_X, XV)                                                  \
    do {                                                                     \
        float hn[8];                                                         \
        _Pragma("unroll")                                                    \
        for (int m = 0; m < 8; ++m) {                                        \
            float ti = fmaf(-L2E,      acc[m][0], bs[m].x);                  \
            float tf = fmaf(-L2E,      acc[m][1], bs[m].y);                  \
            float tg = fmaf(2.f * L2E, acc[m][2], bs[m].z);                  \
            float to = fmaf(-L2E,      acc[m][3], bs[m].w);                  \
            if (USE_X) {                                                     \
                ti = fmaf(w0s[m].x, (XV), ti);                               \
                tf = fmaf(w0s[m].y, (XV), tf);                               \
                tg = fmaf(w0s[m].z, (XV), tg);                               \
                to = fmaf(w0s[m].w, (XV), to);                               \
            }                                                                \
            const float ii = rcp1p(__builtin_amdgcn_exp2f(ti));              \
            const float ff = rcp1p(__builtin_amdgcn_exp2f(tf));              \
            const float gz = fmaf(-2.f, rcp1p(__builtin_amdgcn_exp2f(tg)), 1.f); \
            const float oo = rcp1p(__builtin_amdgcn_exp2f(to));              \
            cst[m] = fmaf(ff, cst[m], ii * gz);                              \
            const float ec = __builtin_amdgcn_exp2f(2.f * L2E * cst[m]);     \
            hn[m] = oo * fmaf(-2.f, rcp1p(ec), 1.f);                         \
        }                                                                    \
        uint4 pk;                                                            \
        pk.x = pk2(hn[0], hn[1]); pk.y = pk2(hn[2], hn[3]);                  \
        pk.z = pk2(hn[4], hn[5]); pk.w = pk2(hn[6], hn[7]);                  \
        hself = __builtin_bit_cast(f16x8, pk);                               \
        fcv = 0.f;                                                           \
        if (lay == 2) {                                                      \
            _Pragma("unroll")                                                \
            for (int m = 0; m < 8; ++m) fcv = fmaf(wfc_r[m], hn[m], fcv);    \
        }                                                                    \
    } while (0)

    const int NIT = T_STEPS / 2 + 2;     // 1026
    int sw = 0, sr = 2;
    for (int n = 0; n < NIT; ++n) {
        f32x4 acc[8];
        float fcv;
        if (lay == 0) {
            // ========== L0: t=2n, 2n+1 (self-chain fully in-register) =====
            if (n < T_STEPS / 2) {
                const int tp = 2 * n + 2;
                const int tA = (tp     < T_STEPS) ? tp     : T_STEPS - 1;
                const int tB = (tp + 1 < T_STEPS) ? tp + 1 : T_STEPS - 1;
                const float xnA = x[tA * NBATCH + b0 + b];   // prefetch
                const float xnB = x[tB * NBATCH + b0 + b];
#pragma unroll
                for (int m = 0; m < 8; ++m) {
                    f32x4 z = {0.f, 0.f, 0.f, 0.f};
                    acc[m] = __builtin_amdgcn_mfma_f32_16x16x32_f16(Fh[m], hself, z, 0, 0, 0);
                }
                ACT_STEP(1, xvA);
                hF0[sw][0][l] = hself;
#pragma unroll
                for (int m = 0; m < 8; ++m) {
                    f32x4 z = {0.f, 0.f, 0.f, 0.f};
                    acc[m] = __builtin_amdgcn_mfma_f32_16x16x32_f16(Fh[m], hself, z, 0, 0, 0);
                }
                ACT_STEP(1, xvB);
                hF0[sw][1][l] = hself;
                xvA = xnA; xvB = xnB;
            }
        } else if (lay == 1) {
            // ========== L1: t=2n-2, 2n-1 ==================================
            if (n >= 1 && n <= T_STEPS / 2) {
                const f16x8 hb0A = hF0[sr][0][l];
                const f16x8 hb0B = hF0[sr][1][l];
#pragma unroll
                for (int m = 0; m < 8; ++m) {
                    f32x4 z = {0.f, 0.f, 0.f, 0.f};
                    z      = __builtin_amdgcn_mfma_f32_16x16x32_f16(Fi[m], hb0A, z, 0, 0, 0);
                    acc[m] = __builtin_amdgcn_mfma_f32_16x16x32_f16(Fh[m], hself, z, 0, 0, 0);
                }
                ACT_STEP(0, 0.f);
                hF1[sw][0][l] = hself;
#pragma unroll
                for (int m = 0; m < 8; ++m) {
                    f32x4 z = {0.f, 0.f, 0.f, 0.f};
                    z      = __builtin_amdgcn_mfma_f32_16x16x32_f16(Fi[m], hb0B, z, 0, 0, 0);
                    acc[m] = __builtin_amdgcn_mfma_f32_16x16x32_f16(Fh[m], hself, z, 0, 0, 0);
                }
                ACT_STEP(0, 0.f);
                hF1[sw][1][l] = hself;
            }
        } else {
            // ========== L2: t=2n-4, 2n-3 (+ direct FC store) ==============
            if (n >= 2 && n <= T_STEPS / 2 + 1) {
                const f16x8 hb1A = hF1[sr][0][l];
                const f16x8 hb1B = hF1[sr][1][l];
#pragma unroll
                for (int m = 0; m < 8; ++m) {
                    f32x4 z = {0.f, 0.f, 0.f, 0.f};
                    z      = __builtin_amdgcn_mfma_f32_16x16x32_f16(Fi[m], hb1A, z, 0, 0, 0);
                    acc[m] = __builtin_amdgcn_mfma_f32_16x16x32_f16(Fh[m], hself, z, 0, 0, 0);
                }
                ACT_STEP(0, 0.f);
                {
                    float v = fcv;
                    v += __shfl_xor(v, 16);
                    v += __shfl_xor(v, 32);
                    if (l < 16) out[(2 * n - 4) * NBATCH + b0 + l] = v + bfc0;
                }
#pragma unroll
                for (int m = 0; m < 8; ++m) {
                    f32x4 z = {0.f, 0.f, 0.f, 0.f};
                    z      = __builtin_amdgcn_mfma_f32_16x16x32_f16(Fi[m], hb1B, z, 0, 0, 0);
                    acc[m] = __builtin_amdgcn_mfma_f32_16x16x32_f16(Fh[m], hself, z, 0, 0, 0);
                }
                ACT_STEP(0, 0.f);
                {
                    float v = fcv;
                    v += __shfl_xor(v, 16);
                    v += __shfl_xor(v, 32);
                    if (l < 16) out[(2 * n - 3) * NBATCH + b0 + l] = v + bfc0;
                }
            }
        }

        sync_lds();                   // slot sr is rewritten >=2 barriers later
        sr = sw; sw = (sw == 2) ? 0 : sw + 1;
    }
#undef ACT_STEP
}

extern "C" void kernel_launch(void* const* d_in, const int* in_sizes, int n_in,
                              void* d_out, int out_size, void* d_ws, size_t ws_size,
                              hipStream_t stream)
{
    const float* x    = (const float*)d_in[0];
    const float* Wih0 = (const float*)d_in[1];
    const float* Whh0 = (const float*)d_in[2];
    const float* bih0 = (const float*)d_in[3];
    const float* bhh0 = (const float*)d_in[4];
    const float* Wih1 = (const float*)d_in[5];
    const float* Whh1 = (const float*)d_in[6];
    const float* bih1 = (const float*)d_in[7];
    const float* bhh1 = (const float*)d_in[8];
    const float* Wih2 = (const float*)d_in[9];
    const float* Whh2 = (const float*)d_in[10];
    const float* bih2 = (const float*)d_in[11];
    const float* bhh2 = (const float*)d_in[12];
    const float* Wfc  = (const float*)d_in[13];
    const float* bfc  = (const float*)d_in[14];
    float* out        = (float*)d_out;

    lstm3_ws3x2_kernel<<<dim3(NBATCH / 16), dim3(192), 0, stream>>>(
        x, Wih0, Whh0, bih0, bhh0,
        Wih1, Whh1, bih1, bhh1,
        Wih2, Whh2, bih2, bhh2,
        Wfc, bfc, out);
}

// Round 14
// 1519.021 us; speedup vs baseline: 4.9959x; 1.0611x over previous
//
#include <hip/hip_runtime.h>

#define T_STEPS 2048
#define NBATCH  1024
#define L2E     1.442695040888963f

typedef _Float16 f16x8 __attribute__((ext_vector_type(8)));
typedef float    f32x4 __attribute__((ext_vector_type(4)));

// pack 2 floats -> 2 fp16 (RTZ) as one u32
__device__ __forceinline__ unsigned pk2(float a, float b) {
    auto v = __builtin_amdgcn_cvt_pkrtz(a, b);
    return __builtin_bit_cast(unsigned, v);
}

// load 8 consecutive fp32 -> 8 fp16 (RNE) fragment
__device__ __forceinline__ f16x8 loadrow8(const float* p) {
    float4 lo = *reinterpret_cast<const float4*>(p);
    float4 hi = *reinterpret_cast<const float4*>(p + 4);
    f16x8 r;
    r[0] = (_Float16)lo.x; r[1] = (_Float16)lo.y;
    r[2] = (_Float16)lo.z; r[3] = (_Float16)lo.w;
    r[4] = (_Float16)hi.x; r[5] = (_Float16)hi.y;
    r[6] = (_Float16)hi.z; r[7] = (_Float16)hi.w;
    return r;
}

// LDS-only barrier (no vmcnt drain -> x prefetch stays in flight)
__device__ __forceinline__ void sync_lds() {
    asm volatile("s_waitcnt lgkmcnt(0)" ::: "memory");
    __builtin_amdgcn_s_barrier();
    asm volatile("" ::: "memory");
}

// Pin an f16x8 into VGPRs (opaque origin -> no remat/reload in the loop)
#define PIN8(f) do { uint4 _u = __builtin_bit_cast(uint4, (f));              \
    asm volatile("" : "+v"(_u.x), "+v"(_u.y), "+v"(_u.z), "+v"(_u.w));       \
    (f) = __builtin_bit_cast(f16x8, _u); } while (0)

// 3 waves per block, one LSTM layer per wave, 16 batch columns per block,
// TWO time-steps per barrier interval, DEEP-SKEW handoffs: consumers use
// data written 2 intervals ago; ds_reads for interval n+1 issue at the top
// of interval n (latency fully hidden). Self-recurrent h stays in registers.
// MFMA layout (verified R6): lane l, tile m holds i,f,g,o of unit 8*(l>>4)+m
// for batch l&15; the lane's 8 per-tile h results ARE its next B-fragment.
// Skew: iter n = {L0: t=2n,2n+1 | L1: t=2n-4,2n-3 | L2: t=2n-8,2n-7 (+FC)}.
// Fused-rcp activations: i*g and o*tanh(c) each use ONE rcp.
__global__ __launch_bounds__(192, 1)
void lstm3_ws3d_kernel(const float* __restrict__ x,
                       const float* __restrict__ Wih0, const float* __restrict__ Whh0,
                       const float* __restrict__ bih0, const float* __restrict__ bhh0,
                       const float* __restrict__ Wih1, const float* __restrict__ Whh1,
                       const float* __restrict__ bih1, const float* __restrict__ bhh1,
                       const float* __restrict__ Wih2, const float* __restrict__ Whh2,
                       const float* __restrict__ bih2, const float* __restrict__ bhh2,
                       const float* __restrict__ Wfc,  const float* __restrict__ bfc,
                       float* __restrict__ out)
{
    const int tid = threadIdx.x;
    const int lay = tid >> 6;         // 0..2 = layer
    const int l   = tid & 63;
    const int g   = l >> 4;           // lane group (k-chunk / C row-group)
    const int b   = l & 15;           // batch column
    const int qa  = l & 3;            // gate index for A-row loads
    const int gp  = (l & 15) >> 2;    // unit group for A-row loads
    const int b0  = blockIdx.x * 16;

    __shared__ __align__(16) f16x8 hF0[3][2][64];   // h0 handoff [slot][step][lane]
    __shared__ __align__(16) f16x8 hF1[3][2][64];   // h1 handoff

    // ---- weight fragments -> registers (pinned) ----
    f16x8 Fi[8], Fh[8];
    {
        const int rowA = qa * 32 + 8 * gp;
        const float* Pi = (lay == 1) ? Wih1 : ((lay == 2) ? Wih2 : nullptr);
        const float* Ph = (lay == 0) ? Whh0 : ((lay == 1) ? Whh1 : Whh2);
#pragma unroll
        for (int m = 0; m < 8; ++m) {
            Fh[m] = loadrow8(Ph + (rowA + m) * 32 + 8 * g);
            PIN8(Fh[m]);
        }
        if (lay != 0) {
#pragma unroll
            for (int m = 0; m < 8; ++m) {
                Fi[m] = loadrow8(Pi + (rowA + m) * 32 + 8 * g);
                PIN8(Fi[m]);
            }
        }
    }

    // ---- biases / Wih0 / Wfc -> registers (pre-scaled by +/-log2e) ----
    float4 bs[8], w0s[8];
    float wfc_r[8];
    {
        const float* BI = (lay == 0) ? bih0 : ((lay == 1) ? bih1 : bih2);
        const float* BH = (lay == 0) ? bhh0 : ((lay == 1) ? bhh1 : bhh2);
#pragma unroll
        for (int m = 0; m < 8; ++m) {
            const int u = 8 * g + m;
            const float bx = BI[u]      + BH[u];
            const float by = BI[u + 32] + BH[u + 32];
            const float bz = BI[u + 64] + BH[u + 64];
            const float bw = BI[u + 96] + BH[u + 96];
            bs[m] = make_float4(-L2E * bx, -L2E * by, 2.f * L2E * bz, -L2E * bw);
            if (lay == 0)
                w0s[m] = make_float4(-L2E * Wih0[u],          -L2E * Wih0[u + 32],
                                     2.f * L2E * Wih0[u + 64], -L2E * Wih0[u + 96]);
            if (lay == 2) wfc_r[m] = Wfc[u];
        }
    }
    const float bfc0 = bfc[0];

    if (lay == 0) {
        f16x8 zz = {0, 0, 0, 0, 0, 0, 0, 0};
        hF0[0][0][l] = zz; hF0[0][1][l] = zz;
        hF0[1][0][l] = zz; hF0[1][1][l] = zz;
        hF0[2][0][l] = zz; hF0[2][1][l] = zz;
    } else if (lay == 1) {
        f16x8 zz = {0, 0, 0, 0, 0, 0, 0, 0};
        hF1[0][0][l] = zz; hF1[0][1][l] = zz;
        hF1[1][0][l] = zz; hF1[1][1][l] = zz;
        hF1[2][0][l] = zz; hF1[2][1][l] = zz;
    }
    __syncthreads();

    float cst[8];
#pragma unroll
    for (int m = 0; m < 8; ++m) cst[m] = 0.f;
    f16x8 hself = {0, 0, 0, 0, 0, 0, 0, 0};   // own layer's h (register)
    f16x8 curA = hself, curB = hself;         // consumed handoff (2-iv-old)
    f16x8 nxtA = hself, nxtB = hself;

    float xvA = 0.f, xvB = 0.f;
    if (lay == 0) { xvA = x[b0 + b]; xvB = x[NBATCH + b0 + b]; }

    // fused-rcp LSTM step: acc[8] -> cst/hself (+fcv for lay2)
#define ACT_STEP(USE_X, XV)                                                  \
    do {                                                                     \
        float hn[8];                                                         \
        _Pragma("unroll")                                                    \
        for (int m = 0; m < 8; ++m) {                                        \
            float ti = fmaf(-L2E,      acc[m][0], bs[m].x);                  \
            float tf = fmaf(-L2E,      acc[m][1], bs[m].y);                  \
            float tg = fmaf(2.f * L2E, acc[m][2], bs[m].z);                  \
            float to = fmaf(-L2E,      acc[m][3], bs[m].w);                  \
            if (USE_X) {                                                     \
                ti = fmaf(w0s[m].x, (XV), ti);                               \
                tf = fmaf(w0s[m].y, (XV), tf);                               \
                tg = fmaf(w0s[m].z, (XV), tg);                               \
                to = fmaf(w0s[m].w, (XV), to);                               \
            }                                                                \
            const float ei = __builtin_amdgcn_exp2f(ti);                     \
            const float ef = __builtin_amdgcn_exp2f(tf);                     \
            const float eg = __builtin_amdgcn_exp2f(tg);                     \
            const float eo = __builtin_amdgcn_exp2f(to);                     \
            const float ig = (eg - 1.f) *                                    \
                __builtin_amdgcn_rcpf((1.f + ei) * (1.f + eg));              \
            const float ff = __builtin_amdgcn_rcpf(1.f + ef);                \
            cst[m] = fmaf(ff, cst[m], ig);                                   \
            const float tc = fminf(2.f * L2E * cst[m], 60.f);                \
            const float ec = __builtin_amdgcn_exp2f(tc);                     \
            hn[m] = (ec - 1.f) *                                             \
                __builtin_amdgcn_rcpf((1.f + eo) * (1.f + ec));              \
        }                                                                    \
        uint4 pk;                                                            \
        pk.x = pk2(hn[0], hn[1]); pk.y = pk2(hn[2], hn[3]);                  \
        pk.z = pk2(hn[4], hn[5]); pk.w = pk2(hn[6], hn[7]);                  \
        hself = __builtin_bit_cast(f16x8, pk);                               \
        fcv = 0.f;                                                           \
        if (lay == 2) {                                                      \
            _Pragma("unroll")                                                \
            for (int m = 0; m < 8; ++m) fcv = fmaf(wfc_r[m], hn[m], fcv);    \
        }                                                                    \
    } while (0)

    const int NIT = T_STEPS / 2 + 4;     // 1028
    int sw = 0, sp = 2;                  // write slot n%3; pre-read slot (n-1)%3
    for (int n = 0; n < NIT; ++n) {
        f32x4 acc[8];
        float fcv;
        if (lay == 0) {
            // ========== L0: t=2n, 2n+1 (self-chain fully in-register) =====
            if (n < T_STEPS / 2) {
                const int tp = 2 * n + 2;
                const int tA = (tp     < T_STEPS) ? tp     : T_STEPS - 1;
                const int tB = (tp + 1 < T_STEPS) ? tp + 1 : T_STEPS - 1;
                const float xnA = x[tA * NBATCH + b0 + b];   // prefetch
                const float xnB = x[tB * NBATCH + b0 + b];
#pragma unroll
                for (int m = 0; m < 8; ++m) {
                    f32x4 z = {0.f, 0.f, 0.f, 0.f};
                    acc[m] = __builtin_amdgcn_mfma_f32_16x16x32_f16(Fh[m], hself, z, 0, 0, 0);
                }
                ACT_STEP(1, xvA);
                hF0[sw][0][l] = hself;
#pragma unroll
                for (int m = 0; m < 8; ++m) {
                    f32x4 z = {0.f, 0.f, 0.f, 0.f};
                    acc[m] = __builtin_amdgcn_mfma_f32_16x16x32_f16(Fh[m], hself, z, 0, 0, 0);
                }
                ACT_STEP(1, xvB);
                hF0[sw][1][l] = hself;
                xvA = xnA; xvB = xnB;
            }
        } else if (lay == 1) {
            // ===== L1: t=2n-4, 2n-3 (consumes hF0 written at n-2, in regs) =
            nxtA = hF0[sp][0][l];        // pre-read for interval n+1
            nxtB = hF0[sp][1][l];
            if (n >= 2 && n <= T_STEPS / 2 + 1) {
#pragma unroll
                for (int m = 0; m < 8; ++m) {
                    f32x4 z = {0.f, 0.f, 0.f, 0.f};
                    z      = __builtin_amdgcn_mfma_f32_16x16x32_f16(Fi[m], curA, z, 0, 0, 0);
                    acc[m] = __builtin_amdgcn_mfma_f32_16x16x32_f16(Fh[m], hself, z, 0, 0, 0);
                }
                ACT_STEP(0, 0.f);
                hF1[sw][0][l] = hself;
#pragma unroll
                for (int m = 0; m < 8; ++m) {
                    f32x4 z = {0.f, 0.f, 0.f, 0.f};
                    z      = __builtin_amdgcn_mfma_f32_16x16x32_f16(Fi[m], curB, z, 0, 0, 0);
                    acc[m] = __builtin_amdgcn_mfma_f32_16x16x32_f16(Fh[m], hself, z, 0, 0, 0);
                }
                ACT_STEP(0, 0.f);
                hF1[sw][1][l] = hself;
            }
        } else {
            // ==== L2: t=2n-8, 2n-7 (consumes hF1 written at n-2) + FC =====
            nxtA = hF1[sp][0][l];        // pre-read for interval n+1
            nxtB = hF1[sp][1][l];
            if (n >= 4 && n <= T_STEPS / 2 + 3) {
#pragma unroll
                for (int m = 0; m < 8; ++m) {
                    f32x4 z = {0.f, 0.f, 0.f, 0.f};
                    z      = __builtin_amdgcn_mfma_f32_16x16x32_f16(Fi[m], curA, z, 0, 0, 0);
                    acc[m] = __builtin_amdgcn_mfma_f32_16x16x32_f16(Fh[m], hself, z, 0, 0, 0);
                }
                ACT_STEP(0, 0.f);
                {
                    float v = fcv;
                    v += __shfl_xor(v, 16);
                    v += __shfl_xor(v, 32);
                    if (l < 16) out[(2 * n - 8) * NBATCH + b0 + l] = v + bfc0;
                }
#pragma unroll
                for (int m = 0; m < 8; ++m) {
                    f32x4 z = {0.f, 0.f, 0.f, 0.f};
                    z      = __builtin_amdgcn_mfma_f32_16x16x32_f16(Fi[m], curB, z, 0, 0, 0);
                    acc[m] = __builtin_amdgcn_mfma_f32_16x16x32_f16(Fh[m], hself, z, 0, 0, 0);
                }
                ACT_STEP(0, 0.f);
                {
                    float v = fcv;
                    v += __shfl_xor(v, 16);
                    v += __shfl_xor(v, 32);
                    if (l < 16) out[(2 * n - 7) * NBATCH + b0 + l] = v + bfc0;
                }
            }
        }

        sync_lds();                   // pre-reads complete; slot lifetimes:
                                      // write n, pre-read n+1, rewrite n+3
        curA = nxtA; curB = nxtB;
        sp = sw; sw = (sw == 2) ? 0 : sw + 1;
    }
#undef ACT_STEP
}

extern "C" void kernel_launch(void* const* d_in, const int* in_sizes, int n_in,
                              void* d_out, int out_size, void* d_ws, size_t ws_size,
                              hipStream_t stream)
{
    const float* x    = (const float*)d_in[0];
    const float* Wih0 = (const float*)d_in[1];
    const float* Whh0 = (const float*)d_in[2];
    const float* bih0 = (const float*)d_in[3];
    const float* bhh0 = (const float*)d_in[4];
    const float* Wih1 = (const float*)d_in[5];
    const float* Whh1 = (const float*)d_in[6];
    const float* bih1 = (const float*)d_in[7];
    const float* bhh1 = (const float*)d_in[8];
    const float* Wih2 = (const float*)d_in[9];
    const float* Whh2 = (const float*)d_in[10];
    const float* bih2 = (const float*)d_in[11];
    const float* bhh2 = (const float*)d_in[12];
    const float* Wfc  = (const float*)d_in[13];
    const float* bfc  = (const float*)d_in[14];
    float* out        = (float*)d_out;

    lstm3_ws3d_kernel<<<dim3(NBATCH / 16), dim3(192), 0, stream>>>(
        x, Wih0, Whh0, bih0, bhh0,
        Wih1, Whh1, bih1, bhh1,
        Wih2, Whh2, bih2, bhh2,
        Wfc, bfc, out);
}